// Round 2
// baseline (2266.328 us; speedup 1.0000x reference)
//
#include <hip/hip_runtime.h>

#define NN 100000
#define NE 1600000
#define BN_EPS 1e-5f

typedef short bf16x8 __attribute__((ext_vector_type(8)));
typedef float f32x4 __attribute__((ext_vector_type(4)));

__device__ __forceinline__ ushort f2bf(float f) {
  union { float f; unsigned u; } cv;
  cv.f = f;
  unsigned u = cv.u;
  u += 0x7fffu + ((u >> 16) & 1u);
  return (ushort)(u >> 16);
}
__device__ __forceinline__ float bf2f(ushort u) {
  union { unsigned u; float f; } cv;
  cv.u = ((unsigned)u) << 16;
  return cv.f;
}

// ---------------- CSR build ----------------
__global__ void hist_kernel(const int* __restrict__ dst, int* __restrict__ counts) {
  int i = blockIdx.x * 256 + threadIdx.x;
  atomicAdd(&counts[dst[i]], 1);
}

#define SB 512
__global__ void scan_blocks(const int* __restrict__ counts, int* __restrict__ offs,
                            int* __restrict__ bsums) {
  __shared__ int s[SB];
  int i = blockIdx.x * SB + threadIdx.x;
  int v = (i < NN) ? counts[i] : 0;
  s[threadIdx.x] = v;
  __syncthreads();
  for (int o = 1; o < SB; o <<= 1) {
    int t = (threadIdx.x >= o) ? s[threadIdx.x - o] : 0;
    __syncthreads();
    s[threadIdx.x] += t;
    __syncthreads();
  }
  if (i < NN) offs[i] = s[threadIdx.x] - v;  // intra-block exclusive
  if (threadIdx.x == SB - 1) bsums[blockIdx.x] = s[SB - 1];
}

__global__ void scan_tops(int* __restrict__ bsums, int nb) {
  __shared__ int s[256];
  int v = (threadIdx.x < nb) ? bsums[threadIdx.x] : 0;
  s[threadIdx.x] = v;
  __syncthreads();
  for (int o = 1; o < 256; o <<= 1) {
    int t = (threadIdx.x >= o) ? s[threadIdx.x - o] : 0;
    __syncthreads();
    s[threadIdx.x] += t;
    __syncthreads();
  }
  if (threadIdx.x < nb) bsums[threadIdx.x] = s[threadIdx.x] - v;  // exclusive
}

__global__ void scan_apply(int* __restrict__ offs, const int* __restrict__ bsums,
                           int* __restrict__ cursor) {
  int i = blockIdx.x * SB + threadIdx.x;
  if (i < NN) {
    int o = offs[i] + bsums[blockIdx.x];
    offs[i] = o;
    cursor[i] = o;
  }
  if (i == 0) offs[NN] = NE;
}

__global__ void reorder_kernel(const int* __restrict__ src, const int* __restrict__ dst,
                               int* __restrict__ cursor, int* __restrict__ ssrc) {
  int i = blockIdx.x * 256 + threadIdx.x;
  int p = atomicAdd(&cursor[dst[i]], 1);
  ssrc[p] = src[i];
}

// gather segment-sum + fused prep: hn_pre = bf16((1+eps)*h + sum_{src in CSR[n]} h[src])
__global__ void gather_kernel(const float* __restrict__ h, const int* __restrict__ offs,
                              const int* __restrict__ ssrc, const float* __restrict__ eps,
                              ushort* __restrict__ hp) {
  int w = blockIdx.x * 4 + (threadIdx.x >> 6);  // node
  int d = threadIdx.x & 63;                     // dim
  int beg = offs[w], end = offs[w + 1];
  float acc = 0.f;
  for (int j = beg; j < end; j += 64) {
    int idx = j + d;
    int sv = (idx < end) ? ssrc[idx] : 0;
    int cnt = end - j;
    if (cnt > 64) cnt = 64;
    int k = 0;
    for (; k + 4 <= cnt; k += 4) {
      int s0 = __shfl(sv, k), s1 = __shfl(sv, k + 1);
      int s2 = __shfl(sv, k + 2), s3 = __shfl(sv, k + 3);
      float v0 = h[s0 * 64 + d], v1 = h[s1 * 64 + d];
      float v2 = h[s2 * 64 + d], v3 = h[s3 * 64 + d];
      acc += (v0 + v1) + (v2 + v3);
    }
    for (; k < cnt; ++k) acc += h[__shfl(sv, k) * 64 + d];
  }
  float hn = fmaf(1.0f + eps[0], h[w * 64 + d], acc);
  hp[w * 64 + d] = f2bf(hn);
}

// ---------------- MLP (MFMA) ----------------
// First MFMA: HID = X*W1 (normal orientation). Hidden transposed via per-wave LDS.
// Second MFMA: operands SWAPPED -> computes OUT^T; C-layout then gives each lane
// row m = lane&15, cols 16t + q*4 + r  => 4 consecutive cols per (t) -> float4 stores.
template <bool STATS, bool BF16SRC, bool EPRE_STORE, bool RESID_BF16>
__global__ void __launch_bounds__(256) mlp_kernel(
    const float* __restrict__ xf, const ushort* __restrict__ xb,
    ushort* __restrict__ xb_out,
    const float* __restrict__ W1, const float* __restrict__ b1,
    const float* __restrict__ W2, const float* __restrict__ b2,
    const float* __restrict__ gamma, const float* __restrict__ beta,
    float* __restrict__ ssum, float* __restrict__ ssq,
    const float* __restrict__ resid_f, const ushort* __restrict__ resid_b,
    float* __restrict__ dout, int M) {
  const int tid = threadIdx.x;
  const int lane = tid & 63;
  const int wave = tid >> 6;
  const int m = lane & 15;
  const int q = lane >> 4;
  const int koff = q * 8;

  __shared__ __align__(16) ushort sW1[64 * 72];
  __shared__ __align__(16) ushort sW2[64 * 72];
  __shared__ __align__(16) ushort sHid[4][16 * 72];

  for (int idx = tid; idx < 64 * 16; idx += 256) {
    int k = idx >> 4, g = (idx & 15) * 4;
    float4 w1 = *(const float4*)(W1 + k * 64 + g);
    float4 w2 = *(const float4*)(W2 + k * 64 + g);
    sW1[(g + 0) * 72 + k] = f2bf(w1.x);
    sW1[(g + 1) * 72 + k] = f2bf(w1.y);
    sW1[(g + 2) * 72 + k] = f2bf(w1.z);
    sW1[(g + 3) * 72 + k] = f2bf(w1.w);
    sW2[(g + 0) * 72 + k] = f2bf(w2.x);
    sW2[(g + 1) * 72 + k] = f2bf(w2.y);
    sW2[(g + 2) * 72 + k] = f2bf(w2.z);
    sW2[(g + 3) * 72 + k] = f2bf(w2.w);
  }
  __syncthreads();

  bf16x8 w1f[4][2], w2f[4][2];
#pragma unroll
  for (int t = 0; t < 4; ++t) {
#pragma unroll
    for (int s = 0; s < 2; ++s) {
      w1f[t][s] = *(const bf16x8*)(&sW1[(16 * t + m) * 72 + 32 * s + koff]);
      w2f[t][s] = *(const bf16x8*)(&sW2[(16 * t + m) * 72 + 32 * s + koff]);
    }
  }

  float b1c[4];
#pragma unroll
  for (int t = 0; t < 4; ++t) b1c[t] = b1[16 * t + m];

  // per-lane output columns: c = 16*(i>>2) + q*4 + (i&3), i in [0,16)
  float b2c[16], scl[16], sft[16];
  const float Minv = 1.0f / (float)M;
#pragma unroll
  for (int i = 0; i < 16; ++i) {
    int c = 16 * (i >> 2) + q * 4 + (i & 3);
    if constexpr (STATS) {
      b2c[i] = b2[c];
    } else {
      float mean = ssum[c] * Minv;
      float var = ssq[c] * Minv - mean * mean;
      float sc = gamma[c] * rsqrtf(var + BN_EPS);
      scl[i] = sc;
      sft[i] = sc * (b2[c] - mean) + beta[c];
    }
  }

  float sacc[16], qacc[16];
  if constexpr (STATS) {
#pragma unroll
    for (int i = 0; i < 16; ++i) { sacc[i] = 0.f; qacc[i] = 0.f; }
  }

  ushort* hw = sHid[wave];
  const int ntiles = M >> 4;
  for (int tile = blockIdx.x * 4 + wave; tile < ntiles; tile += gridDim.x * 4) {
    const int r0 = tile << 4;
    const int rowoff = (r0 + m) * 64;
    bf16x8 a0, a1;
    if constexpr (BF16SRC) {
      a0 = *(const bf16x8*)(xb + rowoff + koff);
      a1 = *(const bf16x8*)(xb + rowoff + 32 + koff);
    } else {
      const float* xp = xf + rowoff + koff;
      float4 p0 = *(const float4*)(xp);
      float4 p1 = *(const float4*)(xp + 4);
      float4 p2 = *(const float4*)(xp + 32);
      float4 p3 = *(const float4*)(xp + 36);
      union { bf16x8 v; ushort s[8]; } u0, u1;
      u0.s[0] = f2bf(p0.x); u0.s[1] = f2bf(p0.y); u0.s[2] = f2bf(p0.z); u0.s[3] = f2bf(p0.w);
      u0.s[4] = f2bf(p1.x); u0.s[5] = f2bf(p1.y); u0.s[6] = f2bf(p1.z); u0.s[7] = f2bf(p1.w);
      u1.s[0] = f2bf(p2.x); u1.s[1] = f2bf(p2.y); u1.s[2] = f2bf(p2.z); u1.s[3] = f2bf(p2.w);
      u1.s[4] = f2bf(p3.x); u1.s[5] = f2bf(p3.y); u1.s[6] = f2bf(p3.z); u1.s[7] = f2bf(p3.w);
      a0 = u0.v;
      a1 = u1.v;
    }
    if constexpr (EPRE_STORE) {
      *(bf16x8*)(xb_out + rowoff + koff) = a0;
      *(bf16x8*)(xb_out + rowoff + 32 + koff) = a1;
    }

    f32x4 acc[4];
#pragma unroll
    for (int t = 0; t < 4; ++t) acc[t] = (f32x4){0.f, 0.f, 0.f, 0.f};
#pragma unroll
    for (int t = 0; t < 4; ++t) {
      acc[t] = __builtin_amdgcn_mfma_f32_16x16x32_bf16(a0, w1f[t][0], acc[t], 0, 0, 0);
      acc[t] = __builtin_amdgcn_mfma_f32_16x16x32_bf16(a1, w1f[t][1], acc[t], 0, 0, 0);
    }

#pragma unroll
    for (int t = 0; t < 4; ++t) {
#pragma unroll
      for (int r = 0; r < 4; ++r) {
        float hv = fmaxf(acc[t][r] + b1c[t], 0.f);
        hw[(q * 4 + r) * 72 + 16 * t + m] = f2bf(hv);
      }
    }
    bf16x8 h0 = *(const bf16x8*)(&hw[m * 72 + koff]);
    bf16x8 h1 = *(const bf16x8*)(&hw[m * 72 + 32 + koff]);

    f32x4 out[4];
#pragma unroll
    for (int t = 0; t < 4; ++t) out[t] = (f32x4){0.f, 0.f, 0.f, 0.f};
#pragma unroll
    for (int t = 0; t < 4; ++t) {
      // swapped operands: OUT^T = W2^T * H^T  (A-frag == B-frag lane mapping)
      out[t] = __builtin_amdgcn_mfma_f32_16x16x32_bf16(w2f[t][0], h0, out[t], 0, 0, 0);
      out[t] = __builtin_amdgcn_mfma_f32_16x16x32_bf16(w2f[t][1], h1, out[t], 0, 0, 0);
    }

    if constexpr (STATS) {
#pragma unroll
      for (int t = 0; t < 4; ++t) {
#pragma unroll
        for (int r = 0; r < 4; ++r) {
          float v = out[t][r] + b2c[t * 4 + r];
          sacc[t * 4 + r] += v;
          qacc[t * 4 + r] += v * v;
        }
      }
    } else {
#pragma unroll
      for (int t = 0; t < 4; ++t) {
        const int c0 = 16 * t + q * 4;
        const int base = rowoff + c0;
        float4 rs;
        if constexpr (RESID_BF16) {
          ushort4 rb = *(const ushort4*)(resid_b + base);
          rs.x = bf2f(rb.x); rs.y = bf2f(rb.y); rs.z = bf2f(rb.z); rs.w = bf2f(rb.w);
        } else {
          rs = *(const float4*)(resid_f + base);
        }
        float4 o;
        o.x = fmaxf(fmaf(out[t][0], scl[t * 4 + 0], sft[t * 4 + 0]), 0.f) + rs.x;
        o.y = fmaxf(fmaf(out[t][1], scl[t * 4 + 1], sft[t * 4 + 1]), 0.f) + rs.y;
        o.z = fmaxf(fmaf(out[t][2], scl[t * 4 + 2], sft[t * 4 + 2]), 0.f) + rs.z;
        o.w = fmaxf(fmaf(out[t][3], scl[t * 4 + 3], sft[t * 4 + 3]), 0.f) + rs.w;
        *(float4*)(dout + base) = o;
      }
    }
  }

  if constexpr (STATS) {
#pragma unroll
    for (int i = 0; i < 16; ++i) {
      float s_ = sacc[i], q_ = qacc[i];
      s_ += __shfl_xor(s_, 1); s_ += __shfl_xor(s_, 2);
      s_ += __shfl_xor(s_, 4); s_ += __shfl_xor(s_, 8);
      q_ += __shfl_xor(q_, 1); q_ += __shfl_xor(q_, 2);
      q_ += __shfl_xor(q_, 4); q_ += __shfl_xor(q_, 8);
      if (m == 0) {
        int c = 16 * (i >> 2) + q * 4 + (i & 3);
        atomicAdd(&ssum[c], s_);
        atomicAdd(&ssq[c], q_);
      }
    }
  }
}

// ---------------- launch ----------------
extern "C" void kernel_launch(void* const* d_in, const int* in_sizes, int n_in,
                              void* d_out, int out_size, void* d_ws, size_t ws_size,
                              hipStream_t stream) {
  const float* h   = (const float*)d_in[0];
  const float* e   = (const float*)d_in[1];
  const int*   src = (const int*)d_in[2];
  const int*   dst = (const int*)d_in[3];
  const float* eps = (const float*)d_in[4];
  const float* W1  = (const float*)d_in[5];
  const float* b1  = (const float*)d_in[6];
  const float* W2  = (const float*)d_in[7];
  const float* b2  = (const float*)d_in[8];
  const float* gh  = (const float*)d_in[9];
  const float* bh  = (const float*)d_in[10];
  const float* ge  = (const float*)d_in[11];
  const float* be  = (const float*)d_in[12];

  float* outh = (float*)d_out;           // [NN,64]
  float* oute = outh + (size_t)NN * 64;  // [NE,64]

  char* ws = (char*)d_ws;
  float* stats   = (float*)(ws);                    // 256 f32
  int*   counts  = (int*)(ws + 1024);               // NN
  int*   offs    = (int*)(ws + 401152);             // NN+1
  int*   cursor  = (int*)(ws + 801280);             // NN
  int*   bsums   = (int*)(ws + 1202048);            // 196
  int*   ssrc    = (int*)(ws + 1202944);            // NE
  ushort* hn_pre = (ushort*)(ws + 7602944);         // NN*64 bf16
  ushort* e_pre  = (ushort*)(ws + 20402944);        // NE*64 bf16
  const size_t EPRE_NEED = 20402944ull + (size_t)NE * 128ull;
  const bool use_epre = ws_size >= EPRE_NEED;

  const int nb = (NN + SB - 1) / SB;  // 196

  // zero stats + counts
  hipMemsetAsync(ws, 0, 1024 + (size_t)NN * 4, stream);

  // CSR build + gather
  hist_kernel<<<NE / 256, 256, 0, stream>>>(dst, counts);
  scan_blocks<<<nb, SB, 0, stream>>>(counts, offs, bsums);
  scan_tops<<<1, 256, 0, stream>>>(bsums, nb);
  scan_apply<<<nb, SB, 0, stream>>>(offs, bsums, cursor);
  reorder_kernel<<<NE / 256, 256, 0, stream>>>(src, dst, cursor, ssrc);
  gather_kernel<<<NN / 4, 256, 0, stream>>>(h, offs, ssrc, eps, hn_pre);

  // stats passes
  if (use_epre) {
    mlp_kernel<true, false, true, false><<<2500, 256, 0, stream>>>(
        e, nullptr, e_pre, W1, b1, W2, b2, nullptr, nullptr,
        stats + 128, stats + 192, nullptr, nullptr, nullptr, NE);
  } else {
    mlp_kernel<true, false, false, false><<<2500, 256, 0, stream>>>(
        e, nullptr, nullptr, W1, b1, W2, b2, nullptr, nullptr,
        stats + 128, stats + 192, nullptr, nullptr, nullptr, NE);
  }
  mlp_kernel<true, true, false, false><<<625, 256, 0, stream>>>(
      nullptr, hn_pre, nullptr, W1, b1, W2, b2, nullptr, nullptr,
      stats + 0, stats + 64, nullptr, nullptr, nullptr, NN);

  // apply passes
  if (use_epre) {
    mlp_kernel<false, true, false, true><<<2500, 256, 0, stream>>>(
        nullptr, e_pre, nullptr, W1, b1, W2, b2, ge, be,
        stats + 128, stats + 192, nullptr, e_pre, oute, NE);
  } else {
    mlp_kernel<false, false, false, false><<<2500, 256, 0, stream>>>(
        e, nullptr, nullptr, W1, b1, W2, b2, ge, be,
        stats + 128, stats + 192, e, nullptr, oute, NE);
  }
  mlp_kernel<false, true, false, false><<<625, 256, 0, stream>>>(
      nullptr, hn_pre, nullptr, W1, b1, W2, b2, gh, bh,
      stats + 0, stats + 64, h, nullptr, outh, NN);
}